// Round 16
// baseline (524.837 us; speedup 1.0000x reference)
//
#include <hip/hip_runtime.h>
#include <hip/hip_bf16.h>

#define N_NODES 100000
#define N_EDGES 600000
#define HD 128
#define NBC 384
#define SCAN_B 98   // ceil(N_NODES/1024)
#define MAXFIX 4096
#define T32 ((N_NODES + 31) / 32)    // 3125 tiles of 32 rows
#define GRID_F 1024                  // high co-residency (LDS 25.6KB/block)
#define CAPB4 4096                   // per-(bucket,region) capacity (mean ~1530)

typedef __attribute__((ext_vector_type(8))) short s8v;
typedef __attribute__((ext_vector_type(4))) short s4v;
typedef __attribute__((ext_vector_type(4))) float f4v;
typedef __hip_bfloat16 bf16;

static __device__ __forceinline__ float bf2f(bf16 v) { return __bfloat162float(v); }
static __device__ __forceinline__ bf16 f2bf(float v) { return __float2bfloat16(v); }
static __device__ __forceinline__ float sh2f(short s) { bf16 h = *(bf16*)&s; return bf2f(h); }
static __device__ __forceinline__ short f2sh(float v) { bf16 h = f2bf(v); return *(short*)&h; }
static __device__ __forceinline__ float ldraw(const void* p, int i, int fp32) {
    return fp32 ? ((const float*)p)[i] : bf2f(((const bf16*)p)[i]);
}

// async global->LDS, 16B per lane; lds dest = wave-uniform base + lane*16
static __device__ __forceinline__ void gl2lds16(const void* g, void* l) {
    __builtin_amdgcn_global_load_lds(
        (const __attribute__((address_space(1))) void*)g,
        (__attribute__((address_space(3))) void*)l, 16, 0, 0);
}

// ================= K1: dtype detect + zero ccount/n0cnt/bcur (no deg!) ======
__global__ void k_init(const unsigned short* __restrict__ wraw, const int* __restrict__ eraw,
                       int* __restrict__ flags, int* __restrict__ ccount,
                       int* __restrict__ n0cnt, int* __restrict__ bcur) {
    int b = blockIdx.x, t = threadIdx.x;
    if (b == 0) {
        if (t < 64) {
            int bad = 0;
            for (int k = 0; k < 16; k++) {
                unsigned int u = ((unsigned int)wraw[t * 16 + k]) << 16;
                float f = fabsf(__uint_as_float(u));
                if (!(f <= 1e4f)) bad = 1;  // catches huge AND NaN
            }
            unsigned long long m = __ballot(bad);
            if (t == 0) {
                flags[0] = m ? 1 : 0;
                flags[1] = (eraw[1] == 0 && eraw[3] == 0 && eraw[5] == 0 && eraw[7] == 0) ? 1 : 0;
            }
        }
    } else {
        if (t < 96) ((int4*)ccount)[t] = make_int4(0, 0, 0, 0);   // 384 ints
        if (t == 96) *n0cnt = 0;
        for (int j = t; j < 4 * SCAN_B; j += 256) bcur[j] = 0;    // 392 region counters
    }
}

// ===== K2: fused front — edges | xin | cc | weight conversions (co-resident) =====
#define F_EDGE 586                    // edge cvt + bucket bin (4-way region reserve)
#define F_XIN  (F_EDGE + 391)         // 977   xin full-row build (wide staged)
#define F_CC   (F_XIN + 98)           // 1075  cc cvt + LDS-hist cluster count
#define F_WU   (F_CC + 192)           // 1267  Wu -> Wuc
#define F_WM   (F_WU + 128)           // 1395  Wm -> Wmc
#define F_WET  (F_WM + 32)            // 1427  Wet
#define F_BC   (F_WET + 1)            // 1428  bc + bcenc + buc
#define F_TR   (F_BC + 2)             // 1430  trc
__global__ void k_ffront(const int* __restrict__ flags,
                         const void* cf_r, const void* slf_r, const void* z_r,
                         const void* tr_r, const void* Wenc_r, const void* benc_r,
                         const void* Wm_r, const void* bm_r, const void* Wu_r,
                         const void* bu_r, const int* __restrict__ e_r,
                         const int* __restrict__ cc_r,
                         bf16* __restrict__ xin, bf16* __restrict__ trc,
                         bf16* __restrict__ Wuc, bf16* __restrict__ Wmc,
                         bf16* __restrict__ buc, int* __restrict__ ccc,
                         int* __restrict__ ccount,
                         bf16* __restrict__ Wet, float* __restrict__ bc,
                         float* __restrict__ bcenc,
                         int* __restrict__ bcur, int* __restrict__ ebuf) {
    __shared__ short scfs[3840];                        // 7.7KB cf staging (bf16)
    __shared__ int hist[SCAN_B], hbase[SCAN_B], lcur[SCAN_B];
    __shared__ int ch[NBC];
    int b = blockIdx.x, t = threadIdx.x;
    int fp32 = flags[0];
    if (b < F_EDGE) {
        // ---- edge cvt + bucket binning ((src<<10)|(dst&1023)); 4-way region reserve
        int i64f = flags[1];
        int e0 = b * 1024;
        int rg = b & 3;                                 // region: contention 586 -> ~147
        if (t < SCAN_B) { hist[t] = 0; lcur[t] = 0; }
        __syncthreads();
        int sv[4], dv[4], bk[4];
#pragma unroll
        for (int k = 0; k < 4; k++) {
            int i = e0 + k * 256 + t;
            if (i < N_EDGES) {
                sv[k] = i64f ? e_r[2 * i] : e_r[i];
                dv[k] = i64f ? e_r[2 * (N_EDGES + i)] : e_r[N_EDGES + i];
                bk[k] = dv[k] >> 10;
                atomicAdd(&hist[bk[k]], 1);
            } else bk[k] = -1;
        }
        __syncthreads();
        if (t < SCAN_B && hist[t] > 0) hbase[t] = atomicAdd(&bcur[rg * SCAN_B + t], hist[t]);
        __syncthreads();
#pragma unroll
        for (int k = 0; k < 4; k++) {
            if (bk[k] >= 0) {
                int rel = hbase[bk[k]] + atomicAdd(&lcur[bk[k]], 1);
                if (rel < CAPB4) ebuf[(bk[k] * 4 + rg) * CAPB4 + rel] = (sv[k] << 10) | (dv[k] & 1023);
            }
        }
    } else if (b < F_XIN) {
        // ---- xin rows: wide staged cf (2-4 parallel 16B loads), raw bf16 copies ----
        int bb = b - F_EDGE;
        int base = bb * 256;
        int cnt = min(3840, 1500000 - base * 15);   // cf elements this block
        if (fp32) {
            const float* cfp = (const float*)cf_r + (size_t)base * 15;
            f4v c0, c1, c2, c3;
            int e0 = t * 4, e1 = (256 + t) * 4, e2 = (512 + t) * 4, e3 = (768 + t) * 4;
            if (e0 < cnt) c0 = *(const f4v*)(cfp + e0);
            if (e1 < cnt) c1 = *(const f4v*)(cfp + e1);
            if (e2 < cnt) c2 = *(const f4v*)(cfp + e2);
            if (e3 < cnt) c3 = *(const f4v*)(cfp + e3);
            if (e0 < cnt) { for (int j = 0; j < 4; j++) scfs[e0 + j] = f2sh(c0[j]); }
            if (e1 < cnt) { for (int j = 0; j < 4; j++) scfs[e1 + j] = f2sh(c1[j]); }
            if (e2 < cnt) { for (int j = 0; j < 4; j++) scfs[e2 + j] = f2sh(c2[j]); }
            if (e3 < cnt) { for (int j = 0; j < 4; j++) scfs[e3 + j] = f2sh(c3[j]); }
        } else {
            const short* cfp = (const short*)cf_r + (size_t)base * 15;
            s8v c0, c1;
            int e0 = t * 8, e1 = (256 + t) * 8;
            if (e0 < cnt) c0 = *(const s8v*)(cfp + e0);
            if (e1 < cnt) c1 = *(const s8v*)(cfp + e1);
            if (e0 < cnt) *(s8v*)(scfs + e0) = c0;
            if (e1 < cnt) *(s8v*)(scfs + e1) = c1;
        }
        __syncthreads();
        int node = base + t;
        if (node >= N_NODES) return;
        short* xr = (short*)xin + (size_t)node * 64;
        const short* c = scfs + t * 15;
        s8v o0, o1;
#pragma unroll
        for (int r = 0; r < 8; r++) o0[r] = c[r];
#pragma unroll
        for (int r = 0; r < 7; r++) o1[r] = c[8 + r];
        o1[7] = fp32 ? f2sh(((const float*)slf_r)[node]) : ((const short*)slf_r)[node];
        if (fp32) {
            const float* zp = (const float*)z_r + (size_t)node * 32;
            f4v z0 = *(const f4v*)(zp +  0), z1 = *(const f4v*)(zp +  4);
            f4v z2 = *(const f4v*)(zp +  8), z3 = *(const f4v*)(zp + 12);
            f4v z4 = *(const f4v*)(zp + 16), z5 = *(const f4v*)(zp + 20);
            f4v z6 = *(const f4v*)(zp + 24), z7 = *(const f4v*)(zp + 28);
            s8v w0, w1, w2, w3;
#pragma unroll
            for (int r = 0; r < 4; r++) {
                w0[r] = f2sh(z0[r]); w0[4 + r] = f2sh(z1[r]);
                w1[r] = f2sh(z2[r]); w1[4 + r] = f2sh(z3[r]);
                w2[r] = f2sh(z4[r]); w2[4 + r] = f2sh(z5[r]);
                w3[r] = f2sh(z6[r]); w3[4 + r] = f2sh(z7[r]);
            }
            *(s8v*)(xr) = o0; *(s8v*)(xr + 8) = o1;
            *(s8v*)(xr + 16) = w0; *(s8v*)(xr + 24) = w1;
            *(s8v*)(xr + 32) = w2; *(s8v*)(xr + 40) = w3;
        } else {
            const short* zp = (const short*)z_r + (size_t)node * 32;
            s8v w0 = *(const s8v*)(zp), w1 = *(const s8v*)(zp + 8);
            s8v w2 = *(const s8v*)(zp + 16), w3 = *(const s8v*)(zp + 24);
            *(s8v*)(xr) = o0; *(s8v*)(xr + 8) = o1;
            *(s8v*)(xr + 16) = w0; *(s8v*)(xr + 24) = w1;
            *(s8v*)(xr + 32) = w2; *(s8v*)(xr + 40) = w3;
        }
        s8v zz = {0, 0, 0, 0, 0, 0, 0, 0};
        *(s8v*)(xr + 48) = zz;
        *(s8v*)(xr + 56) = zz;
    } else if (b < F_CC) {
        // ---- cc cvt + cluster count via LDS histogram (98 blocks x 1024 nodes) ----
        int i64f = flags[1];
        int nbase = (b - F_XIN) << 10;
        int nlim = min(1024, N_NODES - nbase);
        for (int j = t; j < NBC; j += 256) ch[j] = 0;
        __syncthreads();
#pragma unroll
        for (int k = 0; k < 4; k++) {
            int li = k * 256 + t;
            if (li < nlim) {
                int i = nbase + li;
                int v = i64f ? cc_r[2 * i] : cc_r[i];
                ccc[i] = v;
                atomicAdd(&ch[v], 1);
            }
        }
        __syncthreads();
        for (int j = t; j < NBC; j += 256) {
            int c = ch[j];
            if (c) atomicAdd(&ccount[j], c);
        }
    } else if (b < F_WU) {
        int i = (b - F_CC) * 256 + t;                 // < 49152
        Wuc[i] = f2bf(ldraw(Wu_r, i, fp32));
    } else if (b < F_WM) {
        int i = (b - F_WU) * 256 + t;                 // < 32768
        Wmc[i] = f2bf(ldraw(Wm_r, i, fp32));
    } else if (b < F_WET) {
        int i = (b - F_WM) * 256 + t;                 // < 8192
        int w = i >> 6, kk = i & 63;
        float v = (kk < 48) ? ldraw(Wenc_r, kk * 128 + w, fp32) : 0.f;
        Wet[i] = f2bf(v);
    } else if (b < F_BC) {
        if (t < 128) {
            float acc = ldraw(bu_r, t, fp32);
#pragma unroll 4
            for (int j = 0; j < 128; j++)
                acc += ldraw(bm_r, j, fp32) * ldraw(Wu_r, (128 + j) * 128 + t, fp32);
            bc[t] = acc;
        } else {
            bcenc[t - 128] = ldraw(benc_r, t - 128, fp32);
            buc[t - 128] = f2bf(ldraw(bu_r, t - 128, fp32));
        }
    } else {
        int i = (b - F_BC) * 256 + t;
        if (i < 384) trc[i] = f2bf(ldraw(tr_r, i, fp32));
    }
}

// ====== K3: tiny scans — bucket-total scan (block 0) + cluster scan (block 1) ====
__global__ void k_scan2(const int* __restrict__ bcur, int* __restrict__ bbase,
                        const int* __restrict__ ccount, int* __restrict__ coff,
                        int* __restrict__ ccur, int* __restrict__ rowptr) {
    __shared__ int sd[1024];
    int t = threadIdx.x;
    if (blockIdx.x == 0) {
        int v = 0;
        if (t < SCAN_B) {
            v = min(bcur[t], CAPB4) + min(bcur[SCAN_B + t], CAPB4)
              + min(bcur[2 * SCAN_B + t], CAPB4) + min(bcur[3 * SCAN_B + t], CAPB4);
        }
        sd[t] = v;
        __syncthreads();
#pragma unroll
        for (int off = 1; off < 128; off <<= 1) {
            int u = (t >= off) ? sd[t - off] : 0;
            __syncthreads();
            sd[t] += u;
            __syncthreads();
        }
        if (t < SCAN_B) bbase[t] = sd[t] - v;
        if (t == 0) rowptr[N_NODES] = N_EDGES;
    } else {
        int v = (t < NBC) ? ccount[t] : 0;
        sd[t] = v;
        __syncthreads();
#pragma unroll
        for (int off = 1; off < 512; off <<= 1) {
            int u = (t >= off) ? sd[t - off] : 0;
            __syncthreads();
            sd[t] += u;
            __syncthreads();
        }
        if (t < NBC) {
            int ex = sd[t] - v;
            coff[t] = ex;
            ccur[t] = ex;
            if (t == NBC - 1) coff[NBC] = sd[t];
        }
    }
}

// == K4: mid (1024t) — Wc compose | pass C CSR | cluster fill | encoder tiles =====
#define M_W  6                   // Wc compose (4 compose + 2 copy blocks)
#define M_PC (M_W + SCAN_B)      // 104   per-bucket CSR: rowptr/deg/n0/colx
#define M_CF (M_PC + SCAN_B)     // 202   cluster-node fill
#define M_EN (M_CF + 391)        // 593   encoder (4 x 64-row tiles per block)
__global__ void k_mid(const bf16* __restrict__ Wmc, const bf16* __restrict__ Wuc,
                      bf16* __restrict__ Wc,
                      const int* __restrict__ ccc, int* __restrict__ ccur,
                      int* __restrict__ cnodes,
                      const int* __restrict__ bcur, const int* __restrict__ bbase,
                      const int* __restrict__ ebuf,
                      int* __restrict__ rowptr, int* __restrict__ deg,
                      int* __restrict__ colx,
                      int* __restrict__ n0list, int* __restrict__ n0cnt,
                      const bf16* __restrict__ xin, const bf16* __restrict__ Wet,
                      const float* __restrict__ bcenc, bf16* __restrict__ xb) {
    __shared__ short wm[4][2048];
    __shared__ int h2[1024], sd[1024];
    __shared__ int h[NBC], cb[NBC];
    int b = blockIdx.x, t = threadIdx.x;
    if (b < M_W) {
        // ---- Wc compose; 4 sub-blocks of 256 threads each ----
        int kw = b;                        // 0..5
        int sub = t >> 8, lt = t & 255;
        int bp = kw * 4 + sub;             // 0..23
        int w = lt & 127, g = lt >> 7;
        int kk0 = bp * 16 + g * 8;
        if (kk0 >= 256) {                  // pure copy region (kw = 4,5 entirely)
            s8v ov;
#pragma unroll
            for (int n = 0; n < 8; n++)
                ov[n] = *((const short*)Wuc + (kk0 + n) * 128 + w);
            *(s8v*)((short*)Wc + w * 384 + kk0) = ov;
            return;
        }
        // stage Wm rows [bp*16, bp*16+16): 2048 shorts per sub-block
        *(s8v*)(wm[sub] + lt * 8) = *(const s8v*)((const short*)Wmc + bp * 2048 + lt * 8);
        __syncthreads();
        float acc[8];
#pragma unroll
        for (int n = 0; n < 8; n++) acc[n] = 0.f;
        const short* wup = (const short*)Wuc + 128 * 128 + w;
        const short* wmb = wm[sub] + (g * 8) * 128;
#pragma unroll 4
        for (int j = 0; j < 128; j++) {
            float wu = sh2f(wup[j * 128]);
#pragma unroll
            for (int n = 0; n < 8; n++)
                acc[n] += sh2f(wmb[n * 128 + j]) * wu;
        }
        s8v ov;
#pragma unroll
        for (int n = 0; n < 8; n++) {
            int kk = kk0 + n;
            float base = (kk < 128) ? sh2f(*((const short*)Wuc + kk * 128 + w)) : 0.f;
            ov[n] = f2sh(acc[n] + base);
        }
        *(s8v*)((short*)Wc + w * 384 + kk0) = ov;
    } else if (b < M_PC) {
        // ---- pass C: per-bucket LDS histogram -> scan -> rowptr/deg/n0 -> colx ----
        int bb = b - M_W;
        int nbase = bb << 10;
        int nlim = min(1024, N_NODES - nbase);
        int base = bbase[bb];
        int cnts[4];
#pragma unroll
        for (int r = 0; r < 4; r++) cnts[r] = min(bcur[r * SCAN_B + bb], CAPB4);
        h2[t] = 0;
        __syncthreads();
#pragma unroll
        for (int r = 0; r < 4; r++) {
            const int* eb = ebuf + (bb * 4 + r) * CAPB4;
            for (int e = t; e < cnts[r]; e += 1024) atomicAdd(&h2[eb[e] & 1023], 1);
        }
        __syncthreads();
        int myDeg = h2[t];
        sd[t] = myDeg;
        __syncthreads();
#pragma unroll
        for (int off = 1; off < 1024; off <<= 1) {
            int u = (t >= off) ? sd[t - off] : 0;
            __syncthreads();
            sd[t] += u;
            __syncthreads();
        }
        int ex = sd[t] - myDeg;
        if (t < nlim) {
            rowptr[nbase + t] = base + ex;
            deg[nbase + t] = myDeg;
            if (myDeg == 0) {
                int p = atomicAdd(n0cnt, 1);
                if (p < MAXFIX) n0list[p] = nbase + t;
            }
        }
        __syncthreads();
        h2[t] = ex;                 // bucket-relative cursor
        __syncthreads();
#pragma unroll
        for (int r = 0; r < 4; r++) {
            const int* eb = ebuf + (bb * 4 + r) * CAPB4;
            for (int e = t; e < cnts[r]; e += 1024) {
                int v = eb[e];
                int p = atomicAdd(&h2[v & 1023], 1);
                colx[base + p] = v >> 10;
            }
        }
    } else if (b < M_CF) {
        // ---- cluster-node fill (1 node/thread, LDS histogram + chunk reserve) ----
        int base = (b - M_PC) << 10;
        int node = base + t;
        if (t < NBC) h[t] = 0;
        __syncthreads();
        int cls = (node < N_NODES) ? ccc[node] : -1;
        if (cls >= 0) atomicAdd(&h[cls], 1);
        __syncthreads();
        if (t < NBC) {
            cb[t] = h[t] ? atomicAdd(&ccur[t], h[t]) : 0;
            h[t] = 0;
        }
        __syncthreads();
        if (cls >= 0) {
            int p = cb[cls] + atomicAdd(&h[cls], 1);
            cnodes[p] = node;
        }
    } else {
        // ---- encoder: xb = bf16(xin[N,64] @ Wet^T + benc); 4 tiles per block ----
        int sub = t >> 8, lt = t & 255;
        int tile = (b - M_CF) * 4 + sub;
        if (tile >= 1563) return;
        int r0 = tile * 64;
        int wave = lt >> 6, lane = lt & 63, quad = lane >> 4, nidx = lane & 15;
        int colbase = wave * 32;
        int arow[4];
#pragma unroll
        for (int rt = 0; rt < 4; rt++) {
            int gr = r0 + rt * 16 + nidx;
            arow[rt] = (gr < N_NODES) ? gr : (N_NODES - 1);
        }
        f4v acc[4][2];
#pragma unroll
        for (int rt = 0; rt < 4; rt++)
#pragma unroll
            for (int ct = 0; ct < 2; ct++) acc[rt][ct] = (f4v){0.f, 0.f, 0.f, 0.f};
#pragma unroll
        for (int s = 0; s < 2; s++) {
            int k0 = s * 32;
            s8v bfrag[4];
#pragma unroll
            for (int rt = 0; rt < 4; rt++)
                bfrag[rt] = *(const s8v*)((const short*)xin + (size_t)arow[rt] * 64 + k0 + quad * 8);
#pragma unroll
            for (int ct = 0; ct < 2; ct++) {
                s8v wfr = *(const s8v*)((const short*)Wet + (colbase + ct * 16 + nidx) * 64 + k0 + quad * 8);
#pragma unroll
                for (int rt = 0; rt < 4; rt++)
                    acc[rt][ct] = __builtin_amdgcn_mfma_f32_16x16x32_bf16(wfr, bfrag[rt], acc[rt][ct], 0, 0, 0);
            }
        }
#pragma unroll
        for (int rt = 0; rt < 4; rt++) {
            int gr = r0 + rt * 16 + nidx;
            if (gr < N_NODES) {
#pragma unroll
                for (int ct = 0; ct < 2; ct++) {
                    int wc0 = colbase + ct * 16 + quad * 4;
                    f4v bv = *(const f4v*)(bcenc + wc0);
                    size_t idx = (size_t)gr * HD + wc0;
                    s4v ob;
#pragma unroll
                    for (int r = 0; r < 4; r++) ob[r] = f2sh(acc[rt][ct][r] + bv[r]);
                    *(s4v*)((short*)xb + idx) = ob;
                }
            }
        }
    }
}

// ====== K6 (per layer): cluster pooling only (384 blocks, 16-row s8v) ======
__global__ void k_pool(const bf16* __restrict__ xb,
                       const int* __restrict__ coff, const int* __restrict__ cnodes,
                       const bf16* __restrict__ trc, bf16* __restrict__ pooled) {
    __shared__ float red[16][128];
    int tid = threadIdx.x;
    int cl = blockIdx.x;
    int lo = coff[cl], hi = coff[cl + 1];
    int cnt = hi - lo;
    int slot = tid >> 4, cg = tid & 15;
    float a[8];
#pragma unroll
    for (int j = 0; j < 8; j++) a[j] = 0.f;
    for (int i = lo + slot; i < hi; i += 16) {
        int nd = cnodes[i];
        s8v v = *(const s8v*)((const short*)xb + (size_t)nd * HD + cg * 8);
#pragma unroll
        for (int j = 0; j < 8; j++) a[j] += sh2f(v[j]);
    }
#pragma unroll
    for (int j = 0; j < 8; j++) red[slot][cg * 8 + j] = a[j];
    __syncthreads();
    if (tid < 128) {
        float s = 0.f;
#pragma unroll
        for (int k = 0; k < 16; k++) s += red[k][tid];
        float v = s / (float)(cnt > 1 ? cnt : 1) * bf2f(trc[cl]);
        pooled[cl * HD + tid] = f2bf(v);
    }
}

// === K7: fused update — inline edge aggregation into swizzled Lm (mb removed) ====
__global__ __launch_bounds__(256, 2) void k_fused2(
    const bf16* __restrict__ xb, const bf16* __restrict__ pooled,
    const bf16* __restrict__ Wc, const float* __restrict__ bc,
    const int* __restrict__ cc, const int* __restrict__ deg,
    const int* __restrict__ rowptr, const int* __restrict__ colx,
    const bf16* __restrict__ Wuc, const bf16* __restrict__ buc,
    const int* __restrict__ n0list, const int* __restrict__ n0cnt,
    bf16* __restrict__ xbo, const int* __restrict__ flags,
    void* __restrict__ out, int last) {
    __shared__ short Lx[32 * 128];
    __shared__ short Lm[32 * 128];
    __shared__ short Lp[32 * 128];
    __shared__ float fxv[128];
    __shared__ float fpv[128];
    int tid = threadIdx.x;
    int wave = tid >> 6, lane = tid & 63, quad = lane >> 4, nidx = lane & 15;
    int colbase = wave * 32;
    int fp32out = flags[0];

    s8v wfr[12][2];
#pragma unroll
    for (int ct = 0; ct < 2; ct++) {
        int wcol = colbase + ((nidx >> 2) << 3) + ct * 4 + (nidx & 3);
        const short* wrow = (const short*)Wc + (size_t)wcol * 384 + quad * 8;
#pragma unroll
        for (int s = 0; s < 12; s++) wfr[s][ct] = *(const s8v*)(wrow + s * 32);
    }
    int cb2 = colbase + quad * 8;
    f4v bv0 = *(const f4v*)(bc + cb2);
    f4v bv1 = *(const f4v*)(bc + cb2 + 4);

    int srow = lane >> 4;
    int sc = lane & 15;
    int half = lane >> 5;     // aggregation: edge-parity half
    int l = lane & 31;        // aggregation: column group (4 cols)

    for (int t = blockIdx.x; t < T32; t += GRID_F) {
        int r0 = t * 32;
        // ---- stage Lx, Lp async (Lm is built by aggregation below) ----
#pragma unroll
        for (int ii = 0; ii < 2; ii++) {
            int i = wave * 2 + ii;            // chunk 0..7, 4 rows each
            int lr = i * 4 + srow;            // row 0..31
            int gr = r0 + lr;
            int grc = (gr < N_NODES) ? gr : (N_NODES - 1);
            int gc = sc ^ (lr & 15);
            gl2lds16((const short*)xb + (size_t)grc * HD + gc * 8, (char*)Lx + i * 1024);
            int ci = cc[grc];
            gl2lds16((const short*)pooled + (size_t)ci * HD + gc * 8, (char*)Lp + i * 1024);
        }
        // ---- inline aggregation: mean of x[src] for this wave's 8 rows -> Lm ----
        for (int rr = 0; rr < 8; rr++) {
            int lr = wave * 8 + rr;
            int node = r0 + lr;
            if (node < N_NODES) {
                int lo = rowptr[node], hi = rowptr[node + 1];
                float a0 = 0.f, a1 = 0.f, a2 = 0.f, a3 = 0.f;
                for (int j0 = lo + half; j0 < hi; j0 += 16) {
                    int idxs[8]; float m[8];
#pragma unroll
                    for (int k = 0; k < 8; k++) {
                        int jj = j0 + 2 * k;
                        idxs[k] = colx[jj < hi ? jj : j0];
                        m[k] = (jj < hi) ? 1.f : 0.f;
                    }
#pragma unroll
                    for (int k = 0; k < 8; k++) {
                        s4v v = *(const s4v*)((const short*)xb + (size_t)idxs[k] * HD + l * 4);
                        a0 += m[k] * sh2f(v[0]);
                        a1 += m[k] * sh2f(v[1]);
                        a2 += m[k] * sh2f(v[2]);
                        a3 += m[k] * sh2f(v[3]);
                    }
                }
                a0 += __shfl_down(a0, 32);
                a1 += __shfl_down(a1, 32);
                a2 += __shfl_down(a2, 32);
                a3 += __shfl_down(a3, 32);
                if (half == 0) {
                    int d = hi - lo;
                    float inv = 1.0f / (float)(d > 1 ? d : 1);
                    // swizzled store: colblock cb at slot cb^(lr&15)
                    int cbk = l >> 1, off = (l & 1) * 4;
                    s4v o;
                    o[0] = f2sh(a0 * inv); o[1] = f2sh(a1 * inv);
                    o[2] = f2sh(a2 * inv); o[3] = f2sh(a3 * inv);
                    *(s4v*)(Lm + lr * 128 + ((cbk ^ (lr & 15)) << 3) + off) = o;
                }
            }
        }
        __syncthreads();

        f4v acc[2][2];
#pragma unroll
        for (int rt = 0; rt < 2; rt++)
#pragma unroll
            for (int ct = 0; ct < 2; ct++) acc[rt][ct] = (f4v){0.f, 0.f, 0.f, 0.f};

#pragma unroll
        for (int s = 0; s < 12; s++) {
            const short* Ls = (s < 4) ? Lx : ((s < 8) ? Lm : Lp);
            int c = (s & 3) * 4 + quad;
            s8v bfrag[2];
#pragma unroll
            for (int rt = 0; rt < 2; rt++) {
                int row = rt * 16 + nidx;
                int slot = c ^ nidx;
                bfrag[rt] = *(const s8v*)(Ls + row * 128 + slot * 8);
            }
#pragma unroll
            for (int ct = 0; ct < 2; ct++)
#pragma unroll
                for (int rt = 0; rt < 2; rt++)
                    acc[rt][ct] = __builtin_amdgcn_mfma_f32_16x16x32_bf16(wfr[s][ct], bfrag[rt], acc[rt][ct], 0, 0, 0);
        }

#pragma unroll
        for (int rt = 0; rt < 2; rt++) {
            int gr = r0 + rt * 16 + nidx;
            if (gr < N_NODES && deg[gr] > 0) {
                int row = rt * 16 + nidx;
                int slot = ((colbase >> 3) + quad) ^ nidx;
                s8v xo = *(const s8v*)(Lx + row * 128 + slot * 8);
                size_t idx = (size_t)gr * HD + cb2;
                float nv[8];
#pragma unroll
                for (int r = 0; r < 4; r++) {
                    float v0 = acc[rt][0][r] + bv0[r];
                    v0 = (v0 > 0.f) ? v0 : 0.01f * v0;
                    nv[r] = sh2f(xo[r]) + v0;
                    float v1 = acc[rt][1][r] + bv1[r];
                    v1 = (v1 > 0.f) ? v1 : 0.01f * v1;
                    nv[4 + r] = sh2f(xo[4 + r]) + v1;
                }
                if (last) {
                    if (fp32out) {
                        f4v o0 = {nv[0], nv[1], nv[2], nv[3]};
                        f4v o1 = {nv[4], nv[5], nv[6], nv[7]};
                        *(f4v*)((float*)out + idx) = o0;
                        *(f4v*)((float*)out + idx + 4) = o1;
                    } else {
                        s8v ob;
#pragma unroll
                        for (int r = 0; r < 8; r++) ob[r] = f2sh(nv[r]);
                        *(s8v*)((short*)out + idx) = ob;
                    }
                } else {
                    s8v ob;
#pragma unroll
                    for (int r = 0; r < 8; r++) ob[r] = f2sh(nv[r]);
                    *(s8v*)((short*)xbo + idx) = ob;
                }
            }
        }
        __syncthreads();
    }

    // ---- deg-0 fixup tail (disjoint rows; fused2 skipped deg==0) ----
    int cnt0 = *n0cnt;
    if (cnt0 > MAXFIX) cnt0 = MAXFIX;
    for (int j = blockIdx.x; j < cnt0; j += gridDim.x) {
        int v = n0list[j];
        if (tid < 128) {
            fxv[tid] = bf2f(xb[(size_t)v * HD + tid]);
            fpv[tid] = bf2f(pooled[cc[v] * HD + tid]);
        }
        __syncthreads();
        if (tid < 128) {
            float acc = bf2f(buc[tid]);
            for (int k = 0; k < 128; k++)
                acc += fxv[k] * bf2f(Wuc[k * 128 + tid]) + fpv[k] * bf2f(Wuc[(256 + k) * 128 + tid]);
            float u = acc > 0.f ? acc : 0.01f * acc;
            size_t idx = (size_t)v * HD + tid;
            float nv = fxv[tid] + u;
            if (last) {
                if (fp32out) ((float*)out)[idx] = nv;
                else ((bf16*)out)[idx] = f2bf(nv);
            } else {
                xbo[idx] = f2bf(nv);
            }
        }
        __syncthreads();
    }
}

extern "C" void kernel_launch(void* const* d_in, const int* in_sizes, int n_in,
                              void* d_out, int out_size, void* d_ws, size_t ws_size,
                              hipStream_t stream) {
    const void* cf_r = d_in[0];
    const void* slf_r = d_in[1];
    const void* z_r = d_in[2];
    const void* tr_r = d_in[3];
    const void* Wenc_r = d_in[4];
    const void* benc_r = d_in[5];
    const void* Wm_r = d_in[6];
    const void* bm_r = d_in[7];
    const void* Wu_r = d_in[8];
    const void* bu_r = d_in[9];
    const int* e_r = (const int*)d_in[10];
    const int* cc_r = (const int*)d_in[11];

    char* w = (char*)d_ws;
    auto alloc = [&](size_t bytes) -> char* {
        char* p = w;
        w += (bytes + 63) & ~(size_t)63;
        return p;
    };
    bf16* xb0 = (bf16*)alloc((size_t)N_NODES * HD * 2);
    bf16* xb1 = (bf16*)alloc((size_t)N_NODES * HD * 2);
    bf16* xin = (bf16*)alloc((size_t)N_NODES * 64 * 2);
    bf16* Wc = (bf16*)alloc(128 * 384 * 2);
    float* bc = (float*)alloc(128 * 4);
    bf16* Wet = (bf16*)alloc(128 * 64 * 2);
    float* bcenc = (float*)alloc(128 * 4);
    bf16* pooled = (bf16*)alloc(NBC * HD * 2);
    int* deg = (int*)alloc(N_NODES * 4);
    int* rowptr = (int*)alloc((N_NODES + 1) * 4);
    int* colx = (int*)alloc(N_EDGES * 4);
    int* ccount = (int*)alloc(NBC * 4);
    int* coff = (int*)alloc((NBC + 1) * 4);
    int* ccur = (int*)alloc(NBC * 4);
    int* cnodes = (int*)alloc(N_NODES * 4);
    int* flags = (int*)alloc(64);
    int* n0list = (int*)alloc(MAXFIX * 4);
    int* n0cnt = (int*)alloc(64);
    bf16* trc = (bf16*)alloc(384 * 2);
    bf16* Wuc = (bf16*)alloc(49152 * 2);
    bf16* Wmc = (bf16*)alloc(32768 * 2);
    bf16* buc = (bf16*)alloc(128 * 2);
    int* ccc = (int*)alloc(N_NODES * 4);
    int* bcur = (int*)alloc(4 * SCAN_B * 4);
    int* bbase = (int*)alloc(SCAN_B * 4);
    int* ebuf = (int*)alloc((size_t)SCAN_B * 4 * CAPB4 * 4);   // 6.4 MB

    // 1) detect dtypes + zero counters (2 blocks)
    k_init<<<2, 256, 0, stream>>>((const unsigned short*)Wenc_r, e_r, flags,
                                  ccount, n0cnt, bcur);
    // 2) fused front: edge binning (4-way regions) + xin + cc-hist + weight cvt
    k_ffront<<<F_TR, 256, 0, stream>>>(flags, cf_r, slf_r, z_r, tr_r, Wenc_r, benc_r,
                                       Wm_r, bm_r, Wu_r, bu_r, e_r, cc_r,
                                       xin, trc, Wuc, Wmc, buc, ccc, ccount,
                                       Wet, bc, bcenc, bcur, ebuf);
    // 3) tiny scans: bucket bases + cluster offsets
    k_scan2<<<2, 1024, 0, stream>>>(bcur, bbase, ccount, coff, ccur, rowptr);
    // 4) mid: Wc compose + per-bucket CSR build + cluster fill + encoder
    k_mid<<<M_EN, 1024, 0, stream>>>(Wmc, Wuc, Wc, ccc, ccur, cnodes,
                                     bcur, bbase, ebuf, rowptr, deg, colx,
                                     n0list, n0cnt, xin, Wet, bcenc, xb0);

    bf16* xbufs[2] = {xb0, xb1};
    for (int layer = 0; layer < 3; layer++) {
        bf16* xbi = xbufs[layer & 1];
        bf16* xbo = xbufs[(layer + 1) & 1];
        int last = (layer == 2);
        k_pool<<<NBC, 256, 0, stream>>>(xbi, coff, cnodes, trc, pooled);
        k_fused2<<<GRID_F, 256, 0, stream>>>(xbi, pooled, Wc, bc, ccc, deg,
                                             rowptr, colx, Wuc, buc,
                                             n0list, n0cnt, xbo, flags, d_out, last);
    }
}

// Round 17
// 358.842 us; speedup vs baseline: 1.4626x; 1.4626x over previous
//
#include <hip/hip_runtime.h>
#include <hip/hip_bf16.h>

#define N_NODES 100000
#define N_EDGES 600000
#define HD 128
#define NBC 384
#define SCAN_B 98   // ceil(N_NODES/1024)
#define MAXFIX 4096
#define T32 ((N_NODES + 31) / 32)    // 3125 tiles of 32 rows
#define GRID_F 1024                  // high co-residency (LDS 25.6KB/block)
#define AGG_B (N_NODES / 4)          // 25000
#define CAPB4 4096                   // per-(bucket,region) capacity (mean ~1530)

typedef __attribute__((ext_vector_type(8))) short s8v;
typedef __attribute__((ext_vector_type(4))) short s4v;
typedef __attribute__((ext_vector_type(4))) float f4v;
typedef __hip_bfloat16 bf16;

static __device__ __forceinline__ float bf2f(bf16 v) { return __bfloat162float(v); }
static __device__ __forceinline__ bf16 f2bf(float v) { return __float2bfloat16(v); }
static __device__ __forceinline__ float sh2f(short s) { bf16 h = *(bf16*)&s; return bf2f(h); }
static __device__ __forceinline__ short f2sh(float v) { bf16 h = f2bf(v); return *(short*)&h; }
static __device__ __forceinline__ float ldraw(const void* p, int i, int fp32) {
    return fp32 ? ((const float*)p)[i] : bf2f(((const bf16*)p)[i]);
}

// async global->LDS, 16B per lane; lds dest = wave-uniform base + lane*16
static __device__ __forceinline__ void gl2lds16(const void* g, void* l) {
    __builtin_amdgcn_global_load_lds(
        (const __attribute__((address_space(1))) void*)g,
        (__attribute__((address_space(3))) void*)l, 16, 0, 0);
}

// ================= K1: dtype detect + zero ccount/n0cnt/bcur (no deg!) ======
__global__ void k_init(const unsigned short* __restrict__ wraw, const int* __restrict__ eraw,
                       int* __restrict__ flags, int* __restrict__ ccount,
                       int* __restrict__ n0cnt, int* __restrict__ bcur) {
    int b = blockIdx.x, t = threadIdx.x;
    if (b == 0) {
        if (t < 64) {
            int bad = 0;
            for (int k = 0; k < 16; k++) {
                unsigned int u = ((unsigned int)wraw[t * 16 + k]) << 16;
                float f = fabsf(__uint_as_float(u));
                if (!(f <= 1e4f)) bad = 1;  // catches huge AND NaN
            }
            unsigned long long m = __ballot(bad);
            if (t == 0) {
                flags[0] = m ? 1 : 0;
                flags[1] = (eraw[1] == 0 && eraw[3] == 0 && eraw[5] == 0 && eraw[7] == 0) ? 1 : 0;
            }
        }
    } else {
        if (t < 96) ((int4*)ccount)[t] = make_int4(0, 0, 0, 0);   // 384 ints
        if (t == 96) *n0cnt = 0;
        for (int j = t; j < 4 * SCAN_B; j += 256) bcur[j] = 0;    // 392 region counters
    }
}

// ===== K2: fused front — edges | xin | cc | weight conversions (co-resident) =====
#define F_EDGE 586                    // edge cvt + bucket bin (4-way region reserve)
#define F_XIN  (F_EDGE + 391)         // 977   xin full-row build (wide staged)
#define F_CC   (F_XIN + 98)           // 1075  cc cvt + LDS-hist cluster count
#define F_WU   (F_CC + 192)           // 1267  Wu -> Wuc
#define F_WM   (F_WU + 128)           // 1395  Wm -> Wmc
#define F_WET  (F_WM + 32)            // 1427  Wet
#define F_BC   (F_WET + 1)            // 1428  bc + bcenc + buc
#define F_TR   (F_BC + 2)             // 1430  trc
__global__ void k_ffront(const int* __restrict__ flags,
                         const void* cf_r, const void* slf_r, const void* z_r,
                         const void* tr_r, const void* Wenc_r, const void* benc_r,
                         const void* Wm_r, const void* bm_r, const void* Wu_r,
                         const void* bu_r, const int* __restrict__ e_r,
                         const int* __restrict__ cc_r,
                         bf16* __restrict__ xin, bf16* __restrict__ trc,
                         bf16* __restrict__ Wuc, bf16* __restrict__ Wmc,
                         bf16* __restrict__ buc, int* __restrict__ ccc,
                         int* __restrict__ ccount,
                         bf16* __restrict__ Wet, float* __restrict__ bc,
                         float* __restrict__ bcenc,
                         int* __restrict__ bcur, int* __restrict__ ebuf) {
    __shared__ short scfs[3840];                        // 7.7KB cf staging (bf16)
    __shared__ int hist[SCAN_B], hbase[SCAN_B], lcur[SCAN_B];
    __shared__ int ch[NBC];
    int b = blockIdx.x, t = threadIdx.x;
    int fp32 = flags[0];
    if (b < F_EDGE) {
        // ---- edge cvt + bucket binning ((src<<10)|(dst&1023)); 4-way region reserve
        int i64f = flags[1];
        int e0 = b * 1024;
        int rg = b & 3;                                 // region: contention 586 -> ~147
        if (t < SCAN_B) { hist[t] = 0; lcur[t] = 0; }
        __syncthreads();
        int sv[4], dv[4], bk[4];
#pragma unroll
        for (int k = 0; k < 4; k++) {
            int i = e0 + k * 256 + t;
            if (i < N_EDGES) {
                sv[k] = i64f ? e_r[2 * i] : e_r[i];
                dv[k] = i64f ? e_r[2 * (N_EDGES + i)] : e_r[N_EDGES + i];
                bk[k] = dv[k] >> 10;
                atomicAdd(&hist[bk[k]], 1);
            } else bk[k] = -1;
        }
        __syncthreads();
        if (t < SCAN_B && hist[t] > 0) hbase[t] = atomicAdd(&bcur[rg * SCAN_B + t], hist[t]);
        __syncthreads();
#pragma unroll
        for (int k = 0; k < 4; k++) {
            if (bk[k] >= 0) {
                int rel = hbase[bk[k]] + atomicAdd(&lcur[bk[k]], 1);
                if (rel < CAPB4) ebuf[(bk[k] * 4 + rg) * CAPB4 + rel] = (sv[k] << 10) | (dv[k] & 1023);
            }
        }
    } else if (b < F_XIN) {
        // ---- xin rows: wide staged cf (2-4 parallel 16B loads), raw bf16 copies ----
        int bb = b - F_EDGE;
        int base = bb * 256;
        int cnt = min(3840, 1500000 - base * 15);   // cf elements this block
        if (fp32) {
            const float* cfp = (const float*)cf_r + (size_t)base * 15;
            f4v c0, c1, c2, c3;
            int e0 = t * 4, e1 = (256 + t) * 4, e2 = (512 + t) * 4, e3 = (768 + t) * 4;
            if (e0 < cnt) c0 = *(const f4v*)(cfp + e0);
            if (e1 < cnt) c1 = *(const f4v*)(cfp + e1);
            if (e2 < cnt) c2 = *(const f4v*)(cfp + e2);
            if (e3 < cnt) c3 = *(const f4v*)(cfp + e3);
            if (e0 < cnt) { for (int j = 0; j < 4; j++) scfs[e0 + j] = f2sh(c0[j]); }
            if (e1 < cnt) { for (int j = 0; j < 4; j++) scfs[e1 + j] = f2sh(c1[j]); }
            if (e2 < cnt) { for (int j = 0; j < 4; j++) scfs[e2 + j] = f2sh(c2[j]); }
            if (e3 < cnt) { for (int j = 0; j < 4; j++) scfs[e3 + j] = f2sh(c3[j]); }
        } else {
            const short* cfp = (const short*)cf_r + (size_t)base * 15;
            s8v c0, c1;
            int e0 = t * 8, e1 = (256 + t) * 8;
            if (e0 < cnt) c0 = *(const s8v*)(cfp + e0);
            if (e1 < cnt) c1 = *(const s8v*)(cfp + e1);
            if (e0 < cnt) *(s8v*)(scfs + e0) = c0;
            if (e1 < cnt) *(s8v*)(scfs + e1) = c1;
        }
        __syncthreads();
        int node = base + t;
        if (node >= N_NODES) return;
        short* xr = (short*)xin + (size_t)node * 64;
        const short* c = scfs + t * 15;
        s8v o0, o1;
#pragma unroll
        for (int r = 0; r < 8; r++) o0[r] = c[r];
#pragma unroll
        for (int r = 0; r < 7; r++) o1[r] = c[8 + r];
        o1[7] = fp32 ? f2sh(((const float*)slf_r)[node]) : ((const short*)slf_r)[node];
        if (fp32) {
            const float* zp = (const float*)z_r + (size_t)node * 32;
            f4v z0 = *(const f4v*)(zp +  0), z1 = *(const f4v*)(zp +  4);
            f4v z2 = *(const f4v*)(zp +  8), z3 = *(const f4v*)(zp + 12);
            f4v z4 = *(const f4v*)(zp + 16), z5 = *(const f4v*)(zp + 20);
            f4v z6 = *(const f4v*)(zp + 24), z7 = *(const f4v*)(zp + 28);
            s8v w0, w1, w2, w3;
#pragma unroll
            for (int r = 0; r < 4; r++) {
                w0[r] = f2sh(z0[r]); w0[4 + r] = f2sh(z1[r]);
                w1[r] = f2sh(z2[r]); w1[4 + r] = f2sh(z3[r]);
                w2[r] = f2sh(z4[r]); w2[4 + r] = f2sh(z5[r]);
                w3[r] = f2sh(z6[r]); w3[4 + r] = f2sh(z7[r]);
            }
            *(s8v*)(xr) = o0; *(s8v*)(xr + 8) = o1;
            *(s8v*)(xr + 16) = w0; *(s8v*)(xr + 24) = w1;
            *(s8v*)(xr + 32) = w2; *(s8v*)(xr + 40) = w3;
        } else {
            const short* zp = (const short*)z_r + (size_t)node * 32;
            s8v w0 = *(const s8v*)(zp), w1 = *(const s8v*)(zp + 8);
            s8v w2 = *(const s8v*)(zp + 16), w3 = *(const s8v*)(zp + 24);
            *(s8v*)(xr) = o0; *(s8v*)(xr + 8) = o1;
            *(s8v*)(xr + 16) = w0; *(s8v*)(xr + 24) = w1;
            *(s8v*)(xr + 32) = w2; *(s8v*)(xr + 40) = w3;
        }
        s8v zz = {0, 0, 0, 0, 0, 0, 0, 0};
        *(s8v*)(xr + 48) = zz;
        *(s8v*)(xr + 56) = zz;
    } else if (b < F_CC) {
        // ---- cc cvt + cluster count via LDS histogram (98 blocks x 1024 nodes) ----
        int i64f = flags[1];
        int nbase = (b - F_XIN) << 10;
        int nlim = min(1024, N_NODES - nbase);
        for (int j = t; j < NBC; j += 256) ch[j] = 0;
        __syncthreads();
#pragma unroll
        for (int k = 0; k < 4; k++) {
            int li = k * 256 + t;
            if (li < nlim) {
                int i = nbase + li;
                int v = i64f ? cc_r[2 * i] : cc_r[i];
                ccc[i] = v;
                atomicAdd(&ch[v], 1);
            }
        }
        __syncthreads();
        for (int j = t; j < NBC; j += 256) {
            int c = ch[j];
            if (c) atomicAdd(&ccount[j], c);
        }
    } else if (b < F_WU) {
        int i = (b - F_CC) * 256 + t;                 // < 49152
        Wuc[i] = f2bf(ldraw(Wu_r, i, fp32));
    } else if (b < F_WM) {
        int i = (b - F_WU) * 256 + t;                 // < 32768
        Wmc[i] = f2bf(ldraw(Wm_r, i, fp32));
    } else if (b < F_WET) {
        int i = (b - F_WM) * 256 + t;                 // < 8192
        int w = i >> 6, kk = i & 63;
        float v = (kk < 48) ? ldraw(Wenc_r, kk * 128 + w, fp32) : 0.f;
        Wet[i] = f2bf(v);
    } else if (b < F_BC) {
        if (t < 128) {
            float acc = ldraw(bu_r, t, fp32);
#pragma unroll 4
            for (int j = 0; j < 128; j++)
                acc += ldraw(bm_r, j, fp32) * ldraw(Wu_r, (128 + j) * 128 + t, fp32);
            bc[t] = acc;
        } else {
            bcenc[t - 128] = ldraw(benc_r, t - 128, fp32);
            buc[t - 128] = f2bf(ldraw(bu_r, t - 128, fp32));
        }
    } else {
        int i = (b - F_BC) * 256 + t;
        if (i < 384) trc[i] = f2bf(ldraw(tr_r, i, fp32));
    }
}

// ====== K3: tiny scans — bucket-total scan (block 0) + cluster scan (block 1) ====
__global__ void k_scan2(const int* __restrict__ bcur, int* __restrict__ bbase,
                        const int* __restrict__ ccount, int* __restrict__ coff,
                        int* __restrict__ ccur, int* __restrict__ rowptr) {
    __shared__ int sd[1024];
    int t = threadIdx.x;
    if (blockIdx.x == 0) {
        int v = 0;
        if (t < SCAN_B) {
            v = min(bcur[t], CAPB4) + min(bcur[SCAN_B + t], CAPB4)
              + min(bcur[2 * SCAN_B + t], CAPB4) + min(bcur[3 * SCAN_B + t], CAPB4);
        }
        sd[t] = v;
        __syncthreads();
#pragma unroll
        for (int off = 1; off < 128; off <<= 1) {
            int u = (t >= off) ? sd[t - off] : 0;
            __syncthreads();
            sd[t] += u;
            __syncthreads();
        }
        if (t < SCAN_B) bbase[t] = sd[t] - v;
        if (t == 0) rowptr[N_NODES] = N_EDGES;
    } else {
        int v = (t < NBC) ? ccount[t] : 0;
        sd[t] = v;
        __syncthreads();
#pragma unroll
        for (int off = 1; off < 512; off <<= 1) {
            int u = (t >= off) ? sd[t - off] : 0;
            __syncthreads();
            sd[t] += u;
            __syncthreads();
        }
        if (t < NBC) {
            int ex = sd[t] - v;
            coff[t] = ex;
            ccur[t] = ex;
            if (t == NBC - 1) coff[NBC] = sd[t];
        }
    }
}

// == K4: mid (1024t) — Wc compose | pass C CSR | cluster fill | encoder tiles =====
#define M_W  6                   // Wc compose (4 compose + 2 copy blocks)
#define M_PC (M_W + SCAN_B)      // 104   per-bucket CSR: rowptr/deg/n0/colx
#define M_CF (M_PC + SCAN_B)     // 202   cluster-node fill
#define M_EN (M_CF + 391)        // 593   encoder (4 x 64-row tiles per block)
__global__ void k_mid(const bf16* __restrict__ Wmc, const bf16* __restrict__ Wuc,
                      bf16* __restrict__ Wc,
                      const int* __restrict__ ccc, int* __restrict__ ccur,
                      int* __restrict__ cnodes,
                      const int* __restrict__ bcur, const int* __restrict__ bbase,
                      const int* __restrict__ ebuf,
                      int* __restrict__ rowptr, int* __restrict__ deg,
                      int* __restrict__ colx,
                      int* __restrict__ n0list, int* __restrict__ n0cnt,
                      const bf16* __restrict__ xin, const bf16* __restrict__ Wet,
                      const float* __restrict__ bcenc, bf16* __restrict__ xb) {
    __shared__ short wm[4][2048];
    __shared__ int h2[1024], sd[1024];
    __shared__ int h[NBC], cb[NBC];
    int b = blockIdx.x, t = threadIdx.x;
    if (b < M_W) {
        // ---- Wc compose; 4 sub-blocks of 256 threads each ----
        int kw = b;                        // 0..5
        int sub = t >> 8, lt = t & 255;
        int bp = kw * 4 + sub;             // 0..23
        int w = lt & 127, g = lt >> 7;
        int kk0 = bp * 16 + g * 8;
        if (kk0 >= 256) {                  // pure copy region (kw = 4,5 entirely)
            s8v ov;
#pragma unroll
            for (int n = 0; n < 8; n++)
                ov[n] = *((const short*)Wuc + (kk0 + n) * 128 + w);
            *(s8v*)((short*)Wc + w * 384 + kk0) = ov;
            return;
        }
        // stage Wm rows [bp*16, bp*16+16): 2048 shorts per sub-block
        *(s8v*)(wm[sub] + lt * 8) = *(const s8v*)((const short*)Wmc + bp * 2048 + lt * 8);
        __syncthreads();
        float acc[8];
#pragma unroll
        for (int n = 0; n < 8; n++) acc[n] = 0.f;
        const short* wup = (const short*)Wuc + 128 * 128 + w;
        const short* wmb = wm[sub] + (g * 8) * 128;
#pragma unroll 4
        for (int j = 0; j < 128; j++) {
            float wu = sh2f(wup[j * 128]);
#pragma unroll
            for (int n = 0; n < 8; n++)
                acc[n] += sh2f(wmb[n * 128 + j]) * wu;
        }
        s8v ov;
#pragma unroll
        for (int n = 0; n < 8; n++) {
            int kk = kk0 + n;
            float base = (kk < 128) ? sh2f(*((const short*)Wuc + kk * 128 + w)) : 0.f;
            ov[n] = f2sh(acc[n] + base);
        }
        *(s8v*)((short*)Wc + w * 384 + kk0) = ov;
    } else if (b < M_PC) {
        // ---- pass C: per-bucket LDS histogram -> scan -> rowptr/deg/n0 -> colx ----
        int bb = b - M_W;
        int nbase = bb << 10;
        int nlim = min(1024, N_NODES - nbase);
        int base = bbase[bb];
        int cnts[4];
#pragma unroll
        for (int r = 0; r < 4; r++) cnts[r] = min(bcur[r * SCAN_B + bb], CAPB4);
        h2[t] = 0;
        __syncthreads();
#pragma unroll
        for (int r = 0; r < 4; r++) {
            const int* eb = ebuf + (bb * 4 + r) * CAPB4;
            for (int e = t; e < cnts[r]; e += 1024) atomicAdd(&h2[eb[e] & 1023], 1);
        }
        __syncthreads();
        int myDeg = h2[t];
        sd[t] = myDeg;
        __syncthreads();
#pragma unroll
        for (int off = 1; off < 1024; off <<= 1) {
            int u = (t >= off) ? sd[t - off] : 0;
            __syncthreads();
            sd[t] += u;
            __syncthreads();
        }
        int ex = sd[t] - myDeg;
        if (t < nlim) {
            rowptr[nbase + t] = base + ex;
            deg[nbase + t] = myDeg;
            if (myDeg == 0) {
                int p = atomicAdd(n0cnt, 1);
                if (p < MAXFIX) n0list[p] = nbase + t;
            }
        }
        __syncthreads();
        h2[t] = ex;                 // bucket-relative cursor
        __syncthreads();
#pragma unroll
        for (int r = 0; r < 4; r++) {
            const int* eb = ebuf + (bb * 4 + r) * CAPB4;
            for (int e = t; e < cnts[r]; e += 1024) {
                int v = eb[e];
                int p = atomicAdd(&h2[v & 1023], 1);
                colx[base + p] = v >> 10;
            }
        }
    } else if (b < M_CF) {
        // ---- cluster-node fill (1 node/thread, LDS histogram + chunk reserve) ----
        int base = (b - M_PC) << 10;
        int node = base + t;
        if (t < NBC) h[t] = 0;
        __syncthreads();
        int cls = (node < N_NODES) ? ccc[node] : -1;
        if (cls >= 0) atomicAdd(&h[cls], 1);
        __syncthreads();
        if (t < NBC) {
            cb[t] = h[t] ? atomicAdd(&ccur[t], h[t]) : 0;
            h[t] = 0;
        }
        __syncthreads();
        if (cls >= 0) {
            int p = cb[cls] + atomicAdd(&h[cls], 1);
            cnodes[p] = node;
        }
    } else {
        // ---- encoder: xb = bf16(xin[N,64] @ Wet^T + benc); 4 tiles per block ----
        int sub = t >> 8, lt = t & 255;
        int tile = (b - M_CF) * 4 + sub;
        if (tile >= 1563) return;
        int r0 = tile * 64;
        int wave = lt >> 6, lane = lt & 63, quad = lane >> 4, nidx = lane & 15;
        int colbase = wave * 32;
        int arow[4];
#pragma unroll
        for (int rt = 0; rt < 4; rt++) {
            int gr = r0 + rt * 16 + nidx;
            arow[rt] = (gr < N_NODES) ? gr : (N_NODES - 1);
        }
        f4v acc[4][2];
#pragma unroll
        for (int rt = 0; rt < 4; rt++)
#pragma unroll
            for (int ct = 0; ct < 2; ct++) acc[rt][ct] = (f4v){0.f, 0.f, 0.f, 0.f};
#pragma unroll
        for (int s = 0; s < 2; s++) {
            int k0 = s * 32;
            s8v bfrag[4];
#pragma unroll
            for (int rt = 0; rt < 4; rt++)
                bfrag[rt] = *(const s8v*)((const short*)xin + (size_t)arow[rt] * 64 + k0 + quad * 8);
#pragma unroll
            for (int ct = 0; ct < 2; ct++) {
                s8v wfr = *(const s8v*)((const short*)Wet + (colbase + ct * 16 + nidx) * 64 + k0 + quad * 8);
#pragma unroll
                for (int rt = 0; rt < 4; rt++)
                    acc[rt][ct] = __builtin_amdgcn_mfma_f32_16x16x32_bf16(wfr, bfrag[rt], acc[rt][ct], 0, 0, 0);
            }
        }
#pragma unroll
        for (int rt = 0; rt < 4; rt++) {
            int gr = r0 + rt * 16 + nidx;
            if (gr < N_NODES) {
#pragma unroll
                for (int ct = 0; ct < 2; ct++) {
                    int wc0 = colbase + ct * 16 + quad * 4;
                    f4v bv = *(const f4v*)(bcenc + wc0);
                    size_t idx = (size_t)gr * HD + wc0;
                    s4v ob;
#pragma unroll
                    for (int r = 0; r < 4; r++) ob[r] = f2sh(acc[rt][ct][r] + bv[r]);
                    *(s4v*)((short*)xb + idx) = ob;
                }
            }
        }
    }
}

// ====== K6 (per layer): cluster pooling (16-row s8v) + edge aggregation =======
__global__ void k_aggpool(const bf16* __restrict__ xb, const int* __restrict__ rowptr,
                          const int* __restrict__ colx, bf16* __restrict__ mb,
                          const int* __restrict__ coff, const int* __restrict__ cnodes,
                          const bf16* __restrict__ trc, bf16* __restrict__ pooled) {
    __shared__ float red[16][128];
    int tid = threadIdx.x;
    if (blockIdx.x < NBC) {
        // ---- pool: 16 node-slots x 16 col-groups, s8v (16B) loads ----
        int cl = blockIdx.x;
        int lo = coff[cl], hi = coff[cl + 1];
        int cnt = hi - lo;
        int slot = tid >> 4, cg = tid & 15;
        float a[8];
#pragma unroll
        for (int j = 0; j < 8; j++) a[j] = 0.f;
        for (int i = lo + slot; i < hi; i += 16) {
            int nd = cnodes[i];
            s8v v = *(const s8v*)((const short*)xb + (size_t)nd * HD + cg * 8);
#pragma unroll
            for (int j = 0; j < 8; j++) a[j] += sh2f(v[j]);
        }
#pragma unroll
        for (int j = 0; j < 8; j++) red[slot][cg * 8 + j] = a[j];
        __syncthreads();
        if (tid < 128) {
            float s = 0.f;
#pragma unroll
            for (int k = 0; k < 16; k++) s += red[k][tid];
            float v = s / (float)(cnt > 1 ? cnt : 1) * bf2f(trc[cl]);
            pooled[cl * HD + tid] = f2bf(v);
        }
        return;
    }
    // ---- aggregation: mean of x[src] over incoming edges; 4 rows in flight ----
    int wave = tid >> 6, lane = tid & 63;
    int node = (blockIdx.x - NBC) * 4 + wave;
    if (node >= N_NODES) return;
    int half = lane >> 5;
    int l = lane & 31;
    int lo = rowptr[node], hi = rowptr[node + 1];
    float a0 = 0.f, a1 = 0.f, a2 = 0.f, a3 = 0.f;
    for (int j0 = lo + half; j0 < hi; j0 += 8) {
        int i1 = j0 + 2, i2 = j0 + 4, i3 = j0 + 6;
        int s0 = colx[j0];
        int s1 = colx[i1 < hi ? i1 : j0];
        int s2 = colx[i2 < hi ? i2 : j0];
        int s3 = colx[i3 < hi ? i3 : j0];
        float m1 = (i1 < hi) ? 1.f : 0.f;
        float m2 = (i2 < hi) ? 1.f : 0.f;
        float m3 = (i3 < hi) ? 1.f : 0.f;
        s4v v0 = *(const s4v*)((const short*)xb + (size_t)s0 * HD + l * 4);
        s4v v1 = *(const s4v*)((const short*)xb + (size_t)s1 * HD + l * 4);
        s4v v2 = *(const s4v*)((const short*)xb + (size_t)s2 * HD + l * 4);
        s4v v3 = *(const s4v*)((const short*)xb + (size_t)s3 * HD + l * 4);
        a0 += sh2f(v0[0]) + m1 * sh2f(v1[0]) + m2 * sh2f(v2[0]) + m3 * sh2f(v3[0]);
        a1 += sh2f(v0[1]) + m1 * sh2f(v1[1]) + m2 * sh2f(v2[1]) + m3 * sh2f(v3[1]);
        a2 += sh2f(v0[2]) + m1 * sh2f(v1[2]) + m2 * sh2f(v2[2]) + m3 * sh2f(v3[2]);
        a3 += sh2f(v0[3]) + m1 * sh2f(v1[3]) + m2 * sh2f(v2[3]) + m3 * sh2f(v3[3]);
    }
    a0 += __shfl_down(a0, 32);
    a1 += __shfl_down(a1, 32);
    a2 += __shfl_down(a2, 32);
    a3 += __shfl_down(a3, 32);
    if (half == 0) {
        int d = hi - lo;
        float inv = 1.0f / (float)(d > 1 ? d : 1);
        s4v o;
        o[0] = f2sh(a0 * inv); o[1] = f2sh(a1 * inv);
        o[2] = f2sh(a2 * inv); o[3] = f2sh(a3 * inv);
        *(s4v*)((short*)mb + (size_t)node * HD + l * 4) = o;
    }
}

// === K7: fused update — 32-row tiles, dedicated fixup LDS, no VGPR clamp =========
__global__ __launch_bounds__(256, 2) void k_fused2(
    const bf16* __restrict__ xb, const bf16* __restrict__ mb, const bf16* __restrict__ pooled,
    const bf16* __restrict__ Wc, const float* __restrict__ bc,
    const int* __restrict__ cc, const int* __restrict__ deg,
    const bf16* __restrict__ Wuc, const bf16* __restrict__ buc,
    const int* __restrict__ n0list, const int* __restrict__ n0cnt,
    bf16* __restrict__ xbo, const int* __restrict__ flags,
    void* __restrict__ out, int last) {
    __shared__ short Lx[32 * 128];
    __shared__ short Lm[32 * 128];
    __shared__ short Lp[32 * 128];
    __shared__ float fxv[128];
    __shared__ float fpv[128];
    int tid = threadIdx.x;
    int wave = tid >> 6, lane = tid & 63, quad = lane >> 4, nidx = lane & 15;
    int colbase = wave * 32;
    int fp32out = flags[0];

    s8v wfr[12][2];
#pragma unroll
    for (int ct = 0; ct < 2; ct++) {
        int wcol = colbase + ((nidx >> 2) << 3) + ct * 4 + (nidx & 3);
        const short* wrow = (const short*)Wc + (size_t)wcol * 384 + quad * 8;
#pragma unroll
        for (int s = 0; s < 12; s++) wfr[s][ct] = *(const s8v*)(wrow + s * 32);
    }
    int cb2 = colbase + quad * 8;
    f4v bv0 = *(const f4v*)(bc + cb2);
    f4v bv1 = *(const f4v*)(bc + cb2 + 4);

    int srow = lane >> 4;
    int sc = lane & 15;

    for (int t = blockIdx.x; t < T32; t += GRID_F) {
        int r0 = t * 32;
#pragma unroll
        for (int ii = 0; ii < 2; ii++) {
            int i = wave * 2 + ii;            // chunk 0..7, 4 rows each
            int lr = i * 4 + srow;            // row 0..31
            int gr = r0 + lr;
            int grc = (gr < N_NODES) ? gr : (N_NODES - 1);
            int gc = sc ^ (lr & 15);
            gl2lds16((const short*)xb + (size_t)grc * HD + gc * 8, (char*)Lx + i * 1024);
            gl2lds16((const short*)mb + (size_t)grc * HD + gc * 8, (char*)Lm + i * 1024);
            int ci = cc[grc];
            gl2lds16((const short*)pooled + (size_t)ci * HD + gc * 8, (char*)Lp + i * 1024);
        }
        __syncthreads();

        f4v acc[2][2];
#pragma unroll
        for (int rt = 0; rt < 2; rt++)
#pragma unroll
            for (int ct = 0; ct < 2; ct++) acc[rt][ct] = (f4v){0.f, 0.f, 0.f, 0.f};

#pragma unroll
        for (int s = 0; s < 12; s++) {
            const short* Ls = (s < 4) ? Lx : ((s < 8) ? Lm : Lp);
            int c = (s & 3) * 4 + quad;
            s8v bfrag[2];
#pragma unroll
            for (int rt = 0; rt < 2; rt++) {
                int row = rt * 16 + nidx;
                int slot = c ^ nidx;
                bfrag[rt] = *(const s8v*)(Ls + row * 128 + slot * 8);
            }
#pragma unroll
            for (int ct = 0; ct < 2; ct++)
#pragma unroll
                for (int rt = 0; rt < 2; rt++)
                    acc[rt][ct] = __builtin_amdgcn_mfma_f32_16x16x32_bf16(wfr[s][ct], bfrag[rt], acc[rt][ct], 0, 0, 0);
        }

#pragma unroll
        for (int rt = 0; rt < 2; rt++) {
            int gr = r0 + rt * 16 + nidx;
            if (gr < N_NODES && deg[gr] > 0) {
                int row = rt * 16 + nidx;
                int slot = ((colbase >> 3) + quad) ^ nidx;
                s8v xo = *(const s8v*)(Lx + row * 128 + slot * 8);
                size_t idx = (size_t)gr * HD + cb2;
                float nv[8];
#pragma unroll
                for (int r = 0; r < 4; r++) {
                    float v0 = acc[rt][0][r] + bv0[r];
                    v0 = (v0 > 0.f) ? v0 : 0.01f * v0;
                    nv[r] = sh2f(xo[r]) + v0;
                    float v1 = acc[rt][1][r] + bv1[r];
                    v1 = (v1 > 0.f) ? v1 : 0.01f * v1;
                    nv[4 + r] = sh2f(xo[4 + r]) + v1;
                }
                if (last) {
                    if (fp32out) {
                        f4v o0 = {nv[0], nv[1], nv[2], nv[3]};
                        f4v o1 = {nv[4], nv[5], nv[6], nv[7]};
                        *(f4v*)((float*)out + idx) = o0;
                        *(f4v*)((float*)out + idx + 4) = o1;
                    } else {
                        s8v ob;
#pragma unroll
                        for (int r = 0; r < 8; r++) ob[r] = f2sh(nv[r]);
                        *(s8v*)((short*)out + idx) = ob;
                    }
                } else {
                    s8v ob;
#pragma unroll
                    for (int r = 0; r < 8; r++) ob[r] = f2sh(nv[r]);
                    *(s8v*)((short*)xbo + idx) = ob;
                }
            }
        }
        __syncthreads();
    }

    // ---- deg-0 fixup tail (disjoint rows; fused2 skipped deg==0) ----
    int cnt0 = *n0cnt;
    if (cnt0 > MAXFIX) cnt0 = MAXFIX;
    for (int j = blockIdx.x; j < cnt0; j += gridDim.x) {
        int v = n0list[j];
        if (tid < 128) {
            fxv[tid] = bf2f(xb[(size_t)v * HD + tid]);
            fpv[tid] = bf2f(pooled[cc[v] * HD + tid]);
        }
        __syncthreads();
        if (tid < 128) {
            float acc = bf2f(buc[tid]);
            for (int k = 0; k < 128; k++)
                acc += fxv[k] * bf2f(Wuc[k * 128 + tid]) + fpv[k] * bf2f(Wuc[(256 + k) * 128 + tid]);
            float u = acc > 0.f ? acc : 0.01f * acc;
            size_t idx = (size_t)v * HD + tid;
            float nv = fxv[tid] + u;
            if (last) {
                if (fp32out) ((float*)out)[idx] = nv;
                else ((bf16*)out)[idx] = f2bf(nv);
            } else {
                xbo[idx] = f2bf(nv);
            }
        }
        __syncthreads();
    }
}

extern "C" void kernel_launch(void* const* d_in, const int* in_sizes, int n_in,
                              void* d_out, int out_size, void* d_ws, size_t ws_size,
                              hipStream_t stream) {
    const void* cf_r = d_in[0];
    const void* slf_r = d_in[1];
    const void* z_r = d_in[2];
    const void* tr_r = d_in[3];
    const void* Wenc_r = d_in[4];
    const void* benc_r = d_in[5];
    const void* Wm_r = d_in[6];
    const void* bm_r = d_in[7];
    const void* Wu_r = d_in[8];
    const void* bu_r = d_in[9];
    const int* e_r = (const int*)d_in[10];
    const int* cc_r = (const int*)d_in[11];

    char* w = (char*)d_ws;
    auto alloc = [&](size_t bytes) -> char* {
        char* p = w;
        w += (bytes + 63) & ~(size_t)63;
        return p;
    };
    bf16* xb0 = (bf16*)alloc((size_t)N_NODES * HD * 2);
    bf16* xb1 = (bf16*)alloc((size_t)N_NODES * HD * 2);
    bf16* mb = (bf16*)alloc((size_t)N_NODES * HD * 2);
    bf16* xin = (bf16*)alloc((size_t)N_NODES * 64 * 2);
    bf16* Wc = (bf16*)alloc(128 * 384 * 2);
    float* bc = (float*)alloc(128 * 4);
    bf16* Wet = (bf16*)alloc(128 * 64 * 2);
    float* bcenc = (float*)alloc(128 * 4);
    bf16* pooled = (bf16*)alloc(NBC * HD * 2);
    int* deg = (int*)alloc(N_NODES * 4);
    int* rowptr = (int*)alloc((N_NODES + 1) * 4);
    int* colx = (int*)alloc(N_EDGES * 4);
    int* ccount = (int*)alloc(NBC * 4);
    int* coff = (int*)alloc((NBC + 1) * 4);
    int* ccur = (int*)alloc(NBC * 4);
    int* cnodes = (int*)alloc(N_NODES * 4);
    int* flags = (int*)alloc(64);
    int* n0list = (int*)alloc(MAXFIX * 4);
    int* n0cnt = (int*)alloc(64);
    bf16* trc = (bf16*)alloc(384 * 2);
    bf16* Wuc = (bf16*)alloc(49152 * 2);
    bf16* Wmc = (bf16*)alloc(32768 * 2);
    bf16* buc = (bf16*)alloc(128 * 2);
    int* ccc = (int*)alloc(N_NODES * 4);
    int* bcur = (int*)alloc(4 * SCAN_B * 4);
    int* bbase = (int*)alloc(SCAN_B * 4);
    int* ebuf = (int*)alloc((size_t)SCAN_B * 4 * CAPB4 * 4);   // 6.4 MB

    // 1) detect dtypes + zero counters (2 blocks)
    k_init<<<2, 256, 0, stream>>>((const unsigned short*)Wenc_r, e_r, flags,
                                  ccount, n0cnt, bcur);
    // 2) fused front: edge binning (4-way regions) + xin + cc-hist + weight cvt
    k_ffront<<<F_TR, 256, 0, stream>>>(flags, cf_r, slf_r, z_r, tr_r, Wenc_r, benc_r,
                                       Wm_r, bm_r, Wu_r, bu_r, e_r, cc_r,
                                       xin, trc, Wuc, Wmc, buc, ccc, ccount,
                                       Wet, bc, bcenc, bcur, ebuf);
    // 3) tiny scans: bucket bases + cluster offsets
    k_scan2<<<2, 1024, 0, stream>>>(bcur, bbase, ccount, coff, ccur, rowptr);
    // 4) mid: Wc compose + per-bucket CSR build + cluster fill + encoder
    k_mid<<<M_EN, 1024, 0, stream>>>(Wmc, Wuc, Wc, ccc, ccur, cnodes,
                                     bcur, bbase, ebuf, rowptr, deg, colx,
                                     n0list, n0cnt, xin, Wet, bcenc, xb0);

    bf16* xbufs[2] = {xb0, xb1};
    for (int layer = 0; layer < 3; layer++) {
        bf16* xbi = xbufs[layer & 1];
        bf16* xbo = xbufs[(layer + 1) & 1];
        int last = (layer == 2);
        k_aggpool<<<AGG_B + NBC, 256, 0, stream>>>(xbi, rowptr, colx, mb,
                                                   coff, cnodes, trc, pooled);
        k_fused2<<<GRID_F, 256, 0, stream>>>(xbi, mb, pooled, Wc, bc, ccc, deg,
                                             Wuc, buc, n0list, n0cnt,
                                             xbo, flags, d_out, last);
    }
}